// Round 1
// 930.173 us; speedup vs baseline: 1.2485x; 1.2485x over previous
//
#include <hip/hip_runtime.h>
#include <hip/hip_bf16.h>

typedef __hip_bfloat16 bf16;
typedef __attribute__((ext_vector_type(8))) short short8;
typedef __attribute__((ext_vector_type(4))) short short4v;
typedef __attribute__((ext_vector_type(4))) float floatx4;

#define BQ 8192
#define ND 9
#define DD 1024
#define HH 4096
#define MM 32768  // 4*BQ

__device__ __forceinline__ short f2bf(float f) {
  unsigned u = __float_as_uint(f);
  u = (u + 0x7fff + ((u >> 16) & 1)) >> 16;  // RNE
  return (short)u;
}

// async global -> LDS, 16B per lane; LDS dest is wave-uniform base + lane*16
__device__ __forceinline__ void async16(const void* g, void* l) {
  __builtin_amdgcn_global_load_lds(
      (const __attribute__((address_space(1))) void*)g,
      (__attribute__((address_space(3))) void*)l, 16, 0, 0);
}

// ---------------------------------------------------------------------------
// Kernel 1: build X (M x D), reads e2..e8 once, emits all 4 target rows.
// ---------------------------------------------------------------------------
__global__ __launch_bounds__(256) void build_x(const float* __restrict__ emb,
                                               bf16* __restrict__ X) {
  int b = blockIdx.x;
  int d = threadIdx.x * 4;
  const float* base = emb + (size_t)b * (ND * DD) + d;

  float e[7][4];
#pragma unroll
  for (int k = 0; k < 7; ++k) *(float4*)e[k] = *(const float4*)(base + (k + 2) * DD);

  auto store = [&](int t, const float* v) {
    short4v o;
#pragma unroll
    for (int c = 0; c < 4; ++c) o[c] = f2bf(v[c]);
    *(short4v*)(X + ((size_t)t * BQ + b) * DD + d) = o;
  };

  float o0[4], o1[4], o2[4], o3[4];
#pragma unroll
  for (int c = 0; c < 4; ++c) {
    o0[c] = 0.1f * e[0][c] - 3.f * e[1][c] + 3.f * e[2][c];
    o1[c] = 3.f * e[0][c] + 3.f * e[1][c] + 0.1f * e[2][c] - 3.f * e[3][c] + 3.f * e[4][c];
    o2[c] = 3.f * e[2][c] + 3.f * e[3][c] + 0.1f * e[4][c] - 3.f * e[5][c] + 3.f * e[6][c];
    o3[c] = 3.f * e[4][c] + 3.f * e[5][c] + 0.1f * e[6][c];
  }
  store(0, o0); store(1, o1); store(2, o2); store(3, o3);
}

// ---------------------------------------------------------------------------
// Kernel 2: transpose fp32 (rows x cols) -> bf16 (cols x rows)
// ---------------------------------------------------------------------------
__global__ void transpose_f2b(const float* __restrict__ src, bf16* __restrict__ dst,
                              int rows, int cols) {
  __shared__ float t[32][33];
  int c0 = blockIdx.x * 32, r0 = blockIdx.y * 32;
  int tx = threadIdx.x, ty = threadIdx.y;
  t[ty][tx] = src[(size_t)(r0 + ty) * cols + (c0 + tx)];
  __syncthreads();
  short v = f2bf(t[tx][ty]);
  dst[(size_t)(c0 + ty) * rows + (r0 + tx)] = *(bf16*)&v;
}

// ---------------------------------------------------------------------------
// Kernel 3: 256x256-tile, BK=64, 8-wave, 8-phase GEMM with counted vmcnt.
// See analysis: staging stream runs 6 phases ahead; vmcnt(4) once per K-tile.
// ---------------------------------------------------------------------------
template <int RELU, typename OutT, int K, int N, int LOGNX>
__global__ __launch_bounds__(512, 2) void gemm256(const bf16* __restrict__ A,
                                                  const bf16* __restrict__ Bt,
                                                  const float* __restrict__ bias,
                                                  OutT* __restrict__ C) {
  constexpr int NT = K / 64;
  __shared__ bf16 sm[65536];  // 128 KiB: [2 buf][A0|A1|B0|B1][128x64]
  char* smc = (char*)sm;
  const bf16* smb = (const bf16*)sm;

  const int tid = threadIdx.x;
  const int l = tid & 63;
  const int wv = tid >> 6;

  const int G = gridDim.x;
  const int b = blockIdx.x;
  const int gb = (b & 7) * (G >> 3) + (b >> 3);
  const int n0 = (gb & ((1 << LOGNX) - 1)) * 256;
  const int m0 = (gb >> LOGNX) * 256;

  const int rowb = wv * 8 + (l >> 3);
  const int kx = ((l & 7) ^ ((l >> 3) & 7)) << 3;  // pre-swizzled global k-off
  const bf16* pA = A + (size_t)(m0 + rowb) * K + kx;
  const bf16* pB = Bt + (size_t)(n0 + rowb) * K + kx;
  const int wlo = wv * 1024;

  const int ra = ((wv >> 1) * 32 + (l & 15)) * 64;
  const int rb = ((wv & 1) * 64 + (l & 15)) * 64;
  const int kg = l >> 4;
  const int sx = l & 7;

  floatx4 acc[4][8];
#pragma unroll
  for (int q = 0; q < 4; ++q)
#pragma unroll
    for (int f = 0; f < 8; ++f)
#pragma unroll
      for (int r = 0; r < 4; ++r) acc[q][f][r] = 0.f;

#define STG(GP, LO)                                            \
  do {                                                         \
    async16((GP), smc + (LO) + wlo);                           \
    async16((GP) + (size_t)64 * K, smc + (LO) + wlo + 8192);   \
  } while (0)

#define LOAD_A(HOFF)                                                          \
  _Pragma("unroll") for (int mf = 0; mf < 2; ++mf)                            \
  _Pragma("unroll") for (int ks = 0; ks < 2; ++ks)                            \
      a[mf][ks] = *(const short8*)(smb + bufe + (HOFF) + ra + mf * 1024 +     \
                                   ((((ks << 2) + kg) ^ sx) << 3));

#define LOAD_B(HOFF)                                                          \
  _Pragma("unroll") for (int nf = 0; nf < 4; ++nf)                            \
  _Pragma("unroll") for (int ks = 0; ks < 2; ++ks)                            \
      bfr[nf][ks] = *(const short8*)(smb + bufe + (HOFF) + rb + nf * 1024 +   \
                                     ((((ks << 2) + kg) ^ sx) << 3));

#define MFMA16(Q)                                                             \
  __builtin_amdgcn_s_setprio(1);                                              \
  _Pragma("unroll") for (int ks = 0; ks < 2; ++ks)                            \
  _Pragma("unroll") for (int mf = 0; mf < 2; ++mf)                            \
  _Pragma("unroll") for (int nf = 0; nf < 4; ++nf)                            \
      acc[Q][mf * 4 + nf] = __builtin_amdgcn_mfma_f32_16x16x32_bf16(          \
          a[mf][ks], bfr[nf][ks], acc[Q][mf * 4 + nf], 0, 0, 0);              \
  __builtin_amdgcn_s_setprio(0);

#define BAR() __builtin_amdgcn_s_barrier()
#define LGKM0() asm volatile("s_waitcnt lgkmcnt(0)" ::: "memory")
#define VM4() asm volatile("s_waitcnt vmcnt(4)" ::: "memory")
#define VM0() asm volatile("s_waitcnt vmcnt(0)" ::: "memory")

  // prologue: stream 0..5 = tile0 [B0,A1,A0,B1] + tile1 [B0,A1]
  STG(pB, 32768);
  STG(pA + (size_t)128 * K, 16384);
  STG(pA, 0);
  STG(pB + (size_t)128 * K, 49152);
  STG(pB + 64, 65536 + 32768);
  STG(pA + (size_t)128 * K + 64, 65536 + 16384);
  VM4();
  BAR();

  for (int t = 0; t < NT; ++t) {
    const int bufe = (t & 1) << 15;
    const int bufn = ((t + 1) & 1) << 16;
    const int bufc = (t & 1) << 16;
    short8 a[2][2], bfr[4][2];

    // phase 0: quadrant (A0,B0)
    LOAD_A(0);
    LOAD_B(16384);
    if (t + 1 < NT) STG(pA + (size_t)(t + 1) * 64, bufn);  // A0(t+1)
    BAR();
    LGKM0();
    MFMA16(0);
    BAR();

    // phase 1: quadrant (A1,B0)
    LOAD_A(8192);
    if (t + 1 < NT) STG(pB + (size_t)128 * K + (size_t)(t + 1) * 64, bufn + 49152);  // B1(t+1)
    BAR();
    LGKM0();
    MFMA16(1);
    BAR();

    // phase 2: quadrant (A1,B1)
    LOAD_B(24576);
    if (t + 2 < NT) STG(pB + (size_t)(t + 2) * 64, bufc + 32768);  // B0(t+2)
    BAR();
    LGKM0();
    MFMA16(2);
    BAR();

    // phase 3: quadrant (A0,B1)
    LOAD_A(0);
    if (t + 2 < NT) STG(pA + (size_t)128 * K + (size_t)(t + 2) * 64, bufc + 16384);  // A1(t+2)
    BAR();
    LGKM0();
    MFMA16(3);
    if (t + 2 < NT) { VM4(); } else { VM0(); }
    BAR();
  }

  const int col0 = n0 + (wv & 1) * 64 + (l & 15);
  const int row0 = m0 + (wv >> 1) * 32 + ((l >> 4) << 2);
#pragma unroll
  for (int q = 0; q < 4; ++q) {
    const int qa = (q == 1 || q == 2) ? 1 : 0;
    const int qb = (q >= 2) ? 1 : 0;
#pragma unroll
    for (int nf = 0; nf < 4; ++nf) {
      const int col = col0 + qb * 128 + nf * 16;
      const float bv = bias[col];
#pragma unroll
      for (int mf = 0; mf < 2; ++mf) {
#pragma unroll
        for (int r = 0; r < 4; ++r) {
          const int row = row0 + qa * 128 + mf * 16 + r;
          float v = acc[q][mf * 4 + nf][r] + bv;
          if (RELU) v = fmaxf(v, 0.f);
          if constexpr (sizeof(OutT) == 2) {
            short s = f2bf(v);
            C[(size_t)row * N + col] = *(OutT*)&s;
          } else {
            C[(size_t)row * N + col] = *(OutT*)&v;
          }
        }
      }
    }
  }
#undef STG
#undef LOAD_A
#undef LOAD_B
#undef MFMA16
#undef BAR
#undef LGKM0
#undef VM4
#undef VM0
}

// ---------------------------------------------------------------------------
extern "C" void kernel_launch(void* const* d_in, const int* in_sizes, int n_in,
                              void* d_out, int out_size, void* d_ws, size_t ws_size,
                              hipStream_t stream) {
  const float* emb = (const float*)d_in[0];
  const float* W1  = (const float*)d_in[1];
  const float* b1  = (const float*)d_in[2];
  const float* W2  = (const float*)d_in[3];
  const float* b2  = (const float*)d_in[4];
  float* out = (float*)d_out;

  char* ws = (char*)d_ws;
  // ws layout: X (64MB) | Y (256MB) | W1t (8MB) | W2t (8MB)  => 336MB
  bf16* X   = (bf16*)(ws);
  bf16* Y   = (bf16*)(ws + (size_t)67108864);
  bf16* W1t = (bf16*)(ws + (size_t)67108864 + (size_t)268435456);
  bf16* W2t = (bf16*)(ws + (size_t)67108864 + (size_t)268435456 + (size_t)8388608);

  build_x<<<dim3(BQ), dim3(256), 0, stream>>>(emb, X);
  transpose_f2b<<<dim3(HH / 32, DD / 32), dim3(32, 32), 0, stream>>>(W1, W1t, DD, HH);
  transpose_f2b<<<dim3(DD / 32, HH / 32), dim3(32, 32), 0, stream>>>(W2, W2t, HH, DD);
  // Y = relu(X @ W1 + b1): 128 x 16 = 2048 blocks, LOGNX=4
  gemm256<1, bf16, DD, HH, 4><<<dim3((MM / 256) * (HH / 256)), dim3(512), 0, stream>>>(X, W1t, b1, Y);
  // out = Y @ W2 + b2: 128 x 4 = 512 blocks, LOGNX=2
  gemm256<0, float, HH, DD, 2><<<dim3((MM / 256) * (DD / 256)), dim3(512), 0, stream>>>(Y, W2t, b2, out);
}